// Round 6
// baseline (321.779 us; speedup 1.0000x reference)
//
#include <hip/hip_runtime.h>

// VanillaGNN: out = A @ relu(A @ (x@W1)) @ W2, A[dst,src]=vals, all inputs f32.
// N=100000, E=1600000, IN=128, HID=128, OUT=64.
// CSR build (hist + multiblock scan + dst-WINDOWED packed scatter: 8 passes so
// scattered writes stay L2-resident -> full-line HBM writes),
// bf16 MFMA GEMMs, bf16-payload SpMM with 4x-unrolled gather ILP.

#define IN_CH  128
#define HID_CH 128
#define OUT_CH 64

typedef __attribute__((ext_vector_type(8))) short  bfrag8;   // 8 bf16 (MFMA A/B)
typedef __attribute__((ext_vector_type(4))) float  f32x4;    // MFMA C/D
typedef __attribute__((ext_vector_type(4))) unsigned short us4;
typedef __attribute__((ext_vector_type(8))) unsigned short us8;

__device__ __forceinline__ unsigned short f2bf(float f) {
    unsigned u = __float_as_uint(f);
    u += 0x7FFFu + ((u >> 16) & 1u);   // round-to-nearest-even
    return (unsigned short)(u >> 16);
}
__device__ __forceinline__ float bf2f(unsigned short u) {
    return __uint_as_float(((unsigned)u) << 16);
}

// ---------------- CSR build ----------------

__global__ void hist_kernel(const int* __restrict__ dst, int* __restrict__ counts, int E) {
    int i = blockIdx.x * blockDim.x + threadIdx.x;
    if (i < E) atomicAdd(&counts[dst[i]], 1);
}

// Per-chunk exclusive scan: excl[i] = local exclusive prefix, btot[b] = chunk sum.
__global__ __launch_bounds__(1024) void scanA(const int* __restrict__ counts,
                                              int* __restrict__ excl,
                                              int* __restrict__ btot, int n) {
    __shared__ int wex[16];
    int t = threadIdx.x, lane = t & 63, w = t >> 6;
    int i = blockIdx.x * 1024 + t;
    int v = (i < n) ? counts[i] : 0;
    int s = v;
    #pragma unroll
    for (int d = 1; d < 64; d <<= 1) {
        int u = __shfl_up(s, d, 64);
        if (lane >= d) s += u;
    }
    if (lane == 63) wex[w] = s;
    __syncthreads();
    if (t == 0) {
        int run = 0;
        #pragma unroll
        for (int j = 0; j < 16; ++j) { int x = wex[j]; wex[j] = run; run += x; }
        btot[blockIdx.x] = run;
    }
    __syncthreads();
    if (i < n) excl[i] = wex[w] + (s - v);
}

// Exclusive scan of chunk totals (nblk <= 128), one block of 128 threads.
__global__ __launch_bounds__(128) void scanB(int* __restrict__ btot, int nblk) {
    __shared__ int t0;
    int t = threadIdx.x, lane = t & 63, w = t >> 6;
    int v = (t < nblk) ? btot[t] : 0;
    int s = v;
    #pragma unroll
    for (int d = 1; d < 64; d <<= 1) {
        int u = __shfl_up(s, d, 64);
        if (lane >= d) s += u;
    }
    if (w == 0 && lane == 63) t0 = s;
    __syncthreads();
    int excl = (s - v) + (w ? t0 : 0);
    if (t < nblk) btot[t] = excl;
}

// Add chunk offsets: row_ptr[i] final, cursor[i] = same (scatter cursors).
__global__ __launch_bounds__(1024) void scanC(int* __restrict__ row_ptr,
                                              int* __restrict__ cursor,
                                              const int* __restrict__ btot, int n, int E) {
    int i = blockIdx.x * 1024 + threadIdx.x;
    if (i < n) {
        int e = row_ptr[i] + btot[blockIdx.x];
        row_ptr[i] = e;
        cursor[i] = e;
    }
    if (i == 0) row_ptr[n] = E;
}

// Windowed scatter: only edges with dst in [lo, hi) this pass. Their packed
// 8B (src,val) writes land in a ~1.6MB sval window -> L2-resident lines fill
// completely -> full-line HBM writes instead of 64B/edge partials.
__global__ void scatter_pass(const int* __restrict__ src, const int* __restrict__ dst,
                             const float* __restrict__ ev, int* __restrict__ cursor,
                             int2* __restrict__ sval, int E, int lo, int hi) {
    int i = blockIdx.x * blockDim.x + threadIdx.x;
    if (i < E) {
        int d = dst[i];
        if (d >= lo && d < hi) {
            int pos = atomicAdd(&cursor[d], 1);
            sval[pos] = make_int2(src[i], __float_as_int(ev[i]));
        }
    }
}

// ---------------- weight cast+transpose (tiny) ----------------

__global__ void castT_w1(const float* __restrict__ W, unsigned short* __restrict__ WT) {
    int idx = blockIdx.x * 256 + threadIdx.x;          // 16384 elems
    int n = idx >> 7, k = idx & 127;                   // WT[n][k] = W[k][n]
    WT[n * 128 + k] = f2bf(W[k * 128 + n]);
}
__global__ void castT_w2(const float* __restrict__ W, unsigned short* __restrict__ WT) {
    int idx = blockIdx.x * 256 + threadIdx.x;          // 8192 elems
    int n = idx >> 7, k = idx & 127;                   // WT[n][k] = W[k*64 + n]
    WT[n * 128 + k] = f2bf(W[(size_t)k * OUT_CH + n]);
}

// ---------------- GEMM1: h1 = bf16(x @ W1), MFMA 16x16x32 ----------------
// Block 128x128, 4 waves, wave tile 32x128 (2x8 mtiles). K=128 (no K loop).

__global__ __launch_bounds__(256) void gemm1_mfma(const float* __restrict__ X,
                                                  const unsigned short* __restrict__ W1T,
                                                  unsigned short* __restrict__ H1, int M) {
    __shared__ __align__(16) unsigned short As[128 * 136];  // [row][k], stride 136 (pad)
    __shared__ __align__(16) unsigned short Bs[128 * 136];  // [n][k]
    const int tid = threadIdx.x;
    const int lane = tid & 63;
    const int w = tid >> 6;
    const int row0 = blockIdx.x * 128;

    // stage A: 128x128 f32 -> bf16 (4096 float4 reads)
    #pragma unroll
    for (int l = 0; l < 16; ++l) {
        int f = tid + l * 256;
        int r = f >> 5, c4 = f & 31;
        int row = row0 + r;
        float4 v = make_float4(0.f, 0.f, 0.f, 0.f);
        if (row < M) v = *reinterpret_cast<const float4*>(&X[(size_t)row * IN_CH + c4 * 4]);
        us4 o; o[0] = f2bf(v.x); o[1] = f2bf(v.y); o[2] = f2bf(v.z); o[3] = f2bf(v.w);
        *reinterpret_cast<us4*>(&As[r * 136 + c4 * 4]) = o;
    }
    // stage B: W1T 128x128 bf16 (2048 ushort8 reads)
    #pragma unroll
    for (int l = 0; l < 8; ++l) {
        int f = tid + l * 256;
        int n = f >> 4, k8 = f & 15;
        us8 v = *reinterpret_cast<const us8*>(&W1T[n * 128 + k8 * 8]);
        *reinterpret_cast<us8*>(&Bs[n * 136 + k8 * 8]) = v;
    }
    __syncthreads();

    f32x4 acc[2][8] = {};
    const int lr = lane & 15;
    const int kb = (lane >> 4) * 8;
    #pragma unroll
    for (int kk = 0; kk < 4; ++kk) {
        bfrag8 a0 = *reinterpret_cast<const bfrag8*>(&As[(w * 32 + lr) * 136 + kk * 32 + kb]);
        bfrag8 a1 = *reinterpret_cast<const bfrag8*>(&As[(w * 32 + 16 + lr) * 136 + kk * 32 + kb]);
        #pragma unroll
        for (int ni = 0; ni < 8; ++ni) {
            bfrag8 b = *reinterpret_cast<const bfrag8*>(&Bs[(ni * 16 + lr) * 136 + kk * 32 + kb]);
            acc[0][ni] = __builtin_amdgcn_mfma_f32_16x16x32_bf16(a0, b, acc[0][ni], 0, 0, 0);
            acc[1][ni] = __builtin_amdgcn_mfma_f32_16x16x32_bf16(a1, b, acc[1][ni], 0, 0, 0);
        }
    }
    // epilogue: C row = (lane>>4)*4 + j, col = lane&15 within each 16x16 tile
    const int rb = row0 + w * 32 + (lane >> 4) * 4;
    #pragma unroll
    for (int mi = 0; mi < 2; ++mi)
        #pragma unroll
        for (int j = 0; j < 4; ++j) {
            int row = rb + mi * 16 + j;
            if (row < M) {
                #pragma unroll
                for (int ni = 0; ni < 8; ++ni)
                    H1[(size_t)row * HID_CH + ni * 16 + lr] = f2bf(acc[mi][ni][j]);
            }
        }
}

// ---------------- GEMM2: h2 = bf16(g1r @ W2), A already bf16 (relu pre-applied) ----------------
// Block 128x64, 4 waves, wave tile 32x64 (2x4 mtiles). K=128.

__global__ __launch_bounds__(256) void gemm2_mfma(const unsigned short* __restrict__ G,
                                                  const unsigned short* __restrict__ W2T,
                                                  unsigned short* __restrict__ H2, int M) {
    __shared__ __align__(16) unsigned short As[128 * 136];
    __shared__ __align__(16) unsigned short Bs[64 * 136];
    const int tid = threadIdx.x;
    const int lane = tid & 63;
    const int w = tid >> 6;
    const int row0 = blockIdx.x * 128;

    #pragma unroll
    for (int l = 0; l < 8; ++l) {
        int f = tid + l * 256;                 // 2048 ushort8
        int r = f >> 4, k8 = f & 15;
        int row = row0 + r;
        us8 v{};
        if (row < M) v = *reinterpret_cast<const us8*>(&G[(size_t)row * HID_CH + k8 * 8]);
        *reinterpret_cast<us8*>(&As[r * 136 + k8 * 8]) = v;
    }
    #pragma unroll
    for (int l = 0; l < 4; ++l) {
        int f = tid + l * 256;                 // 1024 ushort8
        int n = f >> 4, k8 = f & 15;
        us8 v = *reinterpret_cast<const us8*>(&W2T[n * 128 + k8 * 8]);
        *reinterpret_cast<us8*>(&Bs[n * 136 + k8 * 8]) = v;
    }
    __syncthreads();

    f32x4 acc[2][4] = {};
    const int lr = lane & 15;
    const int kb = (lane >> 4) * 8;
    #pragma unroll
    for (int kk = 0; kk < 4; ++kk) {
        bfrag8 a0 = *reinterpret_cast<const bfrag8*>(&As[(w * 32 + lr) * 136 + kk * 32 + kb]);
        bfrag8 a1 = *reinterpret_cast<const bfrag8*>(&As[(w * 32 + 16 + lr) * 136 + kk * 32 + kb]);
        #pragma unroll
        for (int ni = 0; ni < 4; ++ni) {
            bfrag8 b = *reinterpret_cast<const bfrag8*>(&Bs[(ni * 16 + lr) * 136 + kk * 32 + kb]);
            acc[0][ni] = __builtin_amdgcn_mfma_f32_16x16x32_bf16(a0, b, acc[0][ni], 0, 0, 0);
            acc[1][ni] = __builtin_amdgcn_mfma_f32_16x16x32_bf16(a1, b, acc[1][ni], 0, 0, 0);
        }
    }
    const int rb = row0 + w * 32 + (lane >> 4) * 4;
    #pragma unroll
    for (int mi = 0; mi < 2; ++mi)
        #pragma unroll
        for (int j = 0; j < 4; ++j) {
            int row = rb + mi * 16 + j;
            if (row < M) {
                #pragma unroll
                for (int ni = 0; ni < 4; ++ni)
                    H2[(size_t)row * OUT_CH + ni * 16 + lr] = f2bf(acc[mi][ni][j]);
            }
        }
}

// ---------------- SpMM: out[i] = sum_e val[e] * h[src[e]], bf16 payload ----------------
// D/8 lanes per node, us8 (16B) gathers, 4x unrolled for gather ILP.
// Edge stream is packed (src:int, val:f32) int2.
// MODE 0: out = f32. MODE 1: out = bf16(relu(acc)).

template <int D, int MODE>
__global__ __launch_bounds__(256) void spmm_bf16(const int* __restrict__ row_ptr,
                                                 const int2* __restrict__ sval,
                                                 const unsigned short* __restrict__ h,
                                                 void* __restrict__ outp, int n) {
    constexpr int TPN = D / 8;
    constexpr int NPB = 256 / TPN;
    int node = blockIdx.x * NPB + threadIdx.x / TPN;
    if (node >= n) return;
    int c8 = (threadIdx.x % TPN) * 8;
    int s = row_ptr[node], e = row_ptr[node + 1];
    float acc[8] = {};
    int i = s;
    for (; i + 4 <= e; i += 4) {
        int2 e0 = sval[i + 0], e1 = sval[i + 1], e2 = sval[i + 2], e3 = sval[i + 3];
        float v0 = __int_as_float(e0.y), v1 = __int_as_float(e1.y);
        float v2 = __int_as_float(e2.y), v3 = __int_as_float(e3.y);
        us8 m0 = *reinterpret_cast<const us8*>(&h[(size_t)e0.x * D + c8]);
        us8 m1 = *reinterpret_cast<const us8*>(&h[(size_t)e1.x * D + c8]);
        us8 m2 = *reinterpret_cast<const us8*>(&h[(size_t)e2.x * D + c8]);
        us8 m3 = *reinterpret_cast<const us8*>(&h[(size_t)e3.x * D + c8]);
        #pragma unroll
        for (int j = 0; j < 8; ++j) {
            acc[j] += v0 * bf2f(m0[j]);
            acc[j] += v1 * bf2f(m1[j]);
            acc[j] += v2 * bf2f(m2[j]);
            acc[j] += v3 * bf2f(m3[j]);
        }
    }
    for (; i < e; ++i) {
        int2 e0 = sval[i];
        float v = __int_as_float(e0.y);
        us8 m = *reinterpret_cast<const us8*>(&h[(size_t)e0.x * D + c8]);
        #pragma unroll
        for (int j = 0; j < 8; ++j) acc[j] += v * bf2f(m[j]);
    }
    if (MODE == 1) {
        us8 o;
        #pragma unroll
        for (int j = 0; j < 8; ++j) o[j] = f2bf(fmaxf(acc[j], 0.f));
        *reinterpret_cast<us8*>(&((unsigned short*)outp)[(size_t)node * D + c8]) = o;
    } else {
        float* op = (float*)outp;
        float4 w0 = make_float4(acc[0], acc[1], acc[2], acc[3]);
        float4 w1 = make_float4(acc[4], acc[5], acc[6], acc[7]);
        *reinterpret_cast<float4*>(&op[(size_t)node * D + c8]) = w0;
        *reinterpret_cast<float4*>(&op[(size_t)node * D + c8 + 4]) = w1;
    }
}

// ---------------- launch ----------------

extern "C" void kernel_launch(void* const* d_in, const int* in_sizes, int n_in,
                              void* d_out, int out_size, void* d_ws, size_t ws_size,
                              hipStream_t stream) {
    const float* x  = (const float*)d_in[0];
    const float* W1 = (const float*)d_in[1];
    const float* W2 = (const float*)d_in[2];
    const float* ev = (const float*)d_in[3];
    const int*   ei = (const int*)d_in[4];

    const int N = in_sizes[0] / IN_CH;   // 100000
    const int E = in_sizes[3];           // 1600000
    const int* src = ei;
    const int* dst = ei + E;

    // workspace layout (~78 MB), bf16 segments first; sval at 8B-aligned offset
    unsigned short* h1   = (unsigned short*)d_ws;        // N*128 bf16
    unsigned short* g1r  = h1 + (size_t)N * HID_CH;      // N*128 bf16 (relu applied)
    unsigned short* h2   = g1r + (size_t)N * HID_CH;     // N*64 bf16
    unsigned short* w1t  = h2 + (size_t)N * OUT_CH;      // 128*128 bf16 [n][k]
    unsigned short* w2t  = w1t + 128 * 128;              // 64*128 bf16 [n][k]
    int2*  sval    = (int2*)(w2t + 64 * 128);            // E packed (src, val)
    int*   row_ptr = (int*)(sval + E);                   // N+1
    int*   cursor  = row_ptr + (N + 1);                  // N (also the histogram)
    int*   btot    = cursor + N;                         // scan chunk totals (<=128)

    const int nchunk = (N + 1023) / 1024;                // 98

    // CSR build
    hipMemsetAsync(cursor, 0, (size_t)N * sizeof(int), stream);
    hist_kernel<<<(E + 255) / 256, 256, 0, stream>>>(dst, cursor, E);
    scanA<<<nchunk, 1024, 0, stream>>>(cursor, row_ptr, btot, N);
    scanB<<<1, 128, 0, stream>>>(btot, nchunk);
    scanC<<<nchunk, 1024, 0, stream>>>(row_ptr, cursor, btot, N, E);

    // dst-windowed scatter: 8 passes, each pass's writes stay in a ~1.6MB
    // L2-resident window of sval (plus a 50KB cursor window).
    const int NPASS = 8;
    const int W = (N + NPASS - 1) / NPASS;               // 12500
    for (int p = 0; p < NPASS; ++p) {
        int lo = p * W;
        int hi = (lo + W < N) ? lo + W : N;
        scatter_pass<<<(E + 255) / 256, 256, 0, stream>>>(src, dst, ev, cursor, sval, E, lo, hi);
    }

    // weights: cast + transpose to [n][k] bf16
    castT_w1<<<64, 256, 0, stream>>>(W1, w1t);
    castT_w2<<<32, 256, 0, stream>>>(W2, w2t);

    // layer 1
    gemm1_mfma<<<(N + 127) / 128, 256, 0, stream>>>(x, w1t, h1, N);
    spmm_bf16<HID_CH, 1><<<(N + 15) / 16, 256, 0, stream>>>(row_ptr, sval, h1, g1r, N);

    // layer 2
    gemm2_mfma<<<(N + 127) / 128, 256, 0, stream>>>(g1r, w2t, h2, N);
    spmm_bf16<OUT_CH, 0><<<(N + 31) / 32, 256, 0, stream>>>(row_ptr, sval, h2, (float*)d_out, N);
}

// Round 7
// 187.643 us; speedup vs baseline: 1.7148x; 1.7148x over previous
//
#include <hip/hip_runtime.h>

// VanillaGNN: out = A @ relu(A @ (x@W1)) @ W2, A[dst,src]=vals, all inputs f32.
// N=100000, E=1600000, IN=128, HID=128, OUT=64.
// CSR build via ATOMIC-FREE two-level counting sort (global atomics execute at
// the memory side on MI355X -> ~40ns each; LDS atomics + scans instead):
//   cnt1: per-block LDS hist over 391 coarse buckets (dst>>8)
//   scanA/B/C2: exclusive scan of (bucket,block) counts
//   scat1: ranked scatter into bucketed ebuf (packed (dst&255)<<24|src, val)
//   sort2: per-bucket 256-bin LDS counting sort -> row_ptr + final sval
// Then bf16 MFMA GEMMs and bf16-payload SpMM with 4x-unrolled gather ILP.

#define IN_CH  128
#define HID_CH 128
#define OUT_CH 64

typedef __attribute__((ext_vector_type(8))) short  bfrag8;   // 8 bf16 (MFMA A/B)
typedef __attribute__((ext_vector_type(4))) float  f32x4;    // MFMA C/D
typedef __attribute__((ext_vector_type(4))) unsigned short us4;
typedef __attribute__((ext_vector_type(8))) unsigned short us8;

__device__ __forceinline__ unsigned short f2bf(float f) {
    unsigned u = __float_as_uint(f);
    u += 0x7FFFu + ((u >> 16) & 1u);   // round-to-nearest-even
    return (unsigned short)(u >> 16);
}
__device__ __forceinline__ float bf2f(unsigned short u) {
    return __uint_as_float(((unsigned)u) << 16);
}

// ---------------- CSR build (no global atomics) ----------------

// Level-1 count: LDS histogram of coarse bucket (dst>>8), one hist per block.
__global__ __launch_bounds__(256) void cnt1(const int* __restrict__ dst,
                                            int* __restrict__ bcnt,
                                            int E, int CH, int NBUCK, int G1) {
    __shared__ int hist[512];
    const int blk = blockIdx.x, t = threadIdx.x;
    for (int j = t; j < NBUCK; j += 256) hist[j] = 0;
    __syncthreads();
    const int lo = blk * CH;
    const int hi = (lo + CH < E) ? lo + CH : E;
    for (int i = lo + t; i < hi; i += 256)
        atomicAdd(&hist[dst[i] >> 8], 1);
    __syncthreads();
    for (int j = t; j < NBUCK; j += 256) bcnt[(size_t)j * G1 + blk] = hist[j];
}

// Per-chunk exclusive scan (in-place safe): excl[i] = local prefix, btot = chunk sum.
__global__ __launch_bounds__(1024) void scanA(const int* __restrict__ counts,
                                              int* __restrict__ excl,
                                              int* __restrict__ btot, int n) {
    __shared__ int wex[16];
    int t = threadIdx.x, lane = t & 63, w = t >> 6;
    int i = blockIdx.x * 1024 + t;
    int v = (i < n) ? counts[i] : 0;
    int s = v;
    #pragma unroll
    for (int d = 1; d < 64; d <<= 1) {
        int u = __shfl_up(s, d, 64);
        if (lane >= d) s += u;
    }
    if (lane == 63) wex[w] = s;
    __syncthreads();
    if (t == 0) {
        int run = 0;
        #pragma unroll
        for (int j = 0; j < 16; ++j) { int x = wex[j]; wex[j] = run; run += x; }
        btot[blockIdx.x] = run;
    }
    __syncthreads();
    if (i < n) excl[i] = wex[w] + (s - v);
}

// Exclusive scan of chunk totals (nblk <= 128), one block of 128 threads.
__global__ __launch_bounds__(128) void scanB(int* __restrict__ btot, int nblk) {
    __shared__ int t0;
    int t = threadIdx.x, lane = t & 63, w = t >> 6;
    int v = (t < nblk) ? btot[t] : 0;
    int s = v;
    #pragma unroll
    for (int d = 1; d < 64; d <<= 1) {
        int u = __shfl_up(s, d, 64);
        if (lane >= d) s += u;
    }
    if (w == 0 && lane == 63) t0 = s;
    __syncthreads();
    int excl = (s - v) + (w ? t0 : 0);
    if (t < nblk) btot[t] = excl;
}

// Add chunk offsets in place.
__global__ __launch_bounds__(1024) void scanC2(int* __restrict__ off,
                                               const int* __restrict__ btot, int n) {
    int i = blockIdx.x * 1024 + threadIdx.x;
    if (i < n) off[i] += btot[blockIdx.x];
}

// Bucket bases: bb[b] = off[b*G1]; bb[NBUCK] = E.
__global__ void bbk(const int* __restrict__ off, int* __restrict__ bb,
                    int NBUCK, int G1, int E) {
    int t = threadIdx.x;
    if (t < NBUCK) bb[t] = off[(size_t)t * G1];
    if (t == NBUCK) bb[t] = E;
}

// Level-1 scatter: rank via LDS cursor, write packed ((dst&255)<<24|src, val).
__global__ __launch_bounds__(256) void scat1(const int* __restrict__ src,
                                             const int* __restrict__ dst,
                                             const float* __restrict__ ev,
                                             const int* __restrict__ off,
                                             int2* __restrict__ ebuf,
                                             int E, int CH, int NBUCK, int G1) {
    __shared__ int cur[512];
    const int blk = blockIdx.x, t = threadIdx.x;
    for (int j = t; j < NBUCK; j += 256) cur[j] = off[(size_t)j * G1 + blk];
    __syncthreads();
    const int lo = blk * CH;
    const int hi = (lo + CH < E) ? lo + CH : E;
    for (int i = lo + t; i < hi; i += 256) {
        int d = dst[i];
        int pos = atomicAdd(&cur[d >> 8], 1);
        ebuf[pos] = make_int2(((d & 255) << 24) | src[i], __float_as_int(ev[i]));
    }
}

// Level-2: per-bucket 256-bin counting sort; emits row_ptr and final sval.
__global__ __launch_bounds__(256) void sort2(const int2* __restrict__ ebuf,
                                             const int* __restrict__ bb,
                                             int2* __restrict__ sval,
                                             int* __restrict__ row_ptr,
                                             int N, int NBUCK, int E) {
    __shared__ int hist[256];
    __shared__ int cur[256];
    __shared__ int wsum[4];
    const int b = blockIdx.x, t = threadIdx.x;
    const int base = bb[b];
    const int cnt = bb[b + 1] - base;
    hist[t] = 0;
    __syncthreads();
    for (int i = base + t; i < base + cnt; i += 256)
        atomicAdd(&hist[(unsigned)ebuf[i].x >> 24], 1);
    __syncthreads();
    // exclusive scan of 256 bins (4 waves)
    int lane = t & 63, w = t >> 6;
    int v = hist[t], s = v;
    #pragma unroll
    for (int d = 1; d < 64; d <<= 1) {
        int u = __shfl_up(s, d, 64);
        if (lane >= d) s += u;
    }
    if (lane == 63) wsum[w] = s;
    __syncthreads();
    if (t == 0) {
        int run = 0;
        #pragma unroll
        for (int j = 0; j < 4; ++j) { int x = wsum[j]; wsum[j] = run; run += x; }
    }
    __syncthreads();
    int excl = wsum[w] + (s - v);
    int node = (b << 8) + t;
    if (node < N) row_ptr[node] = base + excl;
    if (b == NBUCK - 1 && t == 0) row_ptr[N] = E;
    cur[t] = excl;
    __syncthreads();
    for (int i = base + t; i < base + cnt; i += 256) {
        int2 e = ebuf[i];
        int bin = (unsigned)e.x >> 24;
        int pos = base + atomicAdd(&cur[bin], 1);
        sval[pos] = make_int2(e.x & 0xFFFFFF, e.y);
    }
}

// ---------------- weight cast+transpose (tiny) ----------------

__global__ void castT_w1(const float* __restrict__ W, unsigned short* __restrict__ WT) {
    int idx = blockIdx.x * 256 + threadIdx.x;          // 16384 elems
    int n = idx >> 7, k = idx & 127;                   // WT[n][k] = W[k][n]
    WT[n * 128 + k] = f2bf(W[k * 128 + n]);
}
__global__ void castT_w2(const float* __restrict__ W, unsigned short* __restrict__ WT) {
    int idx = blockIdx.x * 256 + threadIdx.x;          // 8192 elems
    int n = idx >> 7, k = idx & 127;                   // WT[n][k] = W[k*64 + n]
    WT[n * 128 + k] = f2bf(W[(size_t)k * OUT_CH + n]);
}

// ---------------- GEMM1: h1 = bf16(x @ W1), MFMA 16x16x32 ----------------
// Block 128x128, 4 waves, wave tile 32x128 (2x8 mtiles). K=128 (no K loop).

__global__ __launch_bounds__(256) void gemm1_mfma(const float* __restrict__ X,
                                                  const unsigned short* __restrict__ W1T,
                                                  unsigned short* __restrict__ H1, int M) {
    __shared__ __align__(16) unsigned short As[128 * 136];  // [row][k], stride 136 (pad)
    __shared__ __align__(16) unsigned short Bs[128 * 136];  // [n][k]
    const int tid = threadIdx.x;
    const int lane = tid & 63;
    const int w = tid >> 6;
    const int row0 = blockIdx.x * 128;

    // stage A: 128x128 f32 -> bf16 (4096 float4 reads)
    #pragma unroll
    for (int l = 0; l < 16; ++l) {
        int f = tid + l * 256;
        int r = f >> 5, c4 = f & 31;
        int row = row0 + r;
        float4 v = make_float4(0.f, 0.f, 0.f, 0.f);
        if (row < M) v = *reinterpret_cast<const float4*>(&X[(size_t)row * IN_CH + c4 * 4]);
        us4 o; o[0] = f2bf(v.x); o[1] = f2bf(v.y); o[2] = f2bf(v.z); o[3] = f2bf(v.w);
        *reinterpret_cast<us4*>(&As[r * 136 + c4 * 4]) = o;
    }
    // stage B: W1T 128x128 bf16 (2048 ushort8 reads)
    #pragma unroll
    for (int l = 0; l < 8; ++l) {
        int f = tid + l * 256;
        int n = f >> 4, k8 = f & 15;
        us8 v = *reinterpret_cast<const us8*>(&W1T[n * 128 + k8 * 8]);
        *reinterpret_cast<us8*>(&Bs[n * 136 + k8 * 8]) = v;
    }
    __syncthreads();

    f32x4 acc[2][8] = {};
    const int lr = lane & 15;
    const int kb = (lane >> 4) * 8;
    #pragma unroll
    for (int kk = 0; kk < 4; ++kk) {
        bfrag8 a0 = *reinterpret_cast<const bfrag8*>(&As[(w * 32 + lr) * 136 + kk * 32 + kb]);
        bfrag8 a1 = *reinterpret_cast<const bfrag8*>(&As[(w * 32 + 16 + lr) * 136 + kk * 32 + kb]);
        #pragma unroll
        for (int ni = 0; ni < 8; ++ni) {
            bfrag8 b = *reinterpret_cast<const bfrag8*>(&Bs[(ni * 16 + lr) * 136 + kk * 32 + kb]);
            acc[0][ni] = __builtin_amdgcn_mfma_f32_16x16x32_bf16(a0, b, acc[0][ni], 0, 0, 0);
            acc[1][ni] = __builtin_amdgcn_mfma_f32_16x16x32_bf16(a1, b, acc[1][ni], 0, 0, 0);
        }
    }
    // epilogue: C row = (lane>>4)*4 + j, col = lane&15 within each 16x16 tile
    const int rb = row0 + w * 32 + (lane >> 4) * 4;
    #pragma unroll
    for (int mi = 0; mi < 2; ++mi)
        #pragma unroll
        for (int j = 0; j < 4; ++j) {
            int row = rb + mi * 16 + j;
            if (row < M) {
                #pragma unroll
                for (int ni = 0; ni < 8; ++ni)
                    H1[(size_t)row * HID_CH + ni * 16 + lr] = f2bf(acc[mi][ni][j]);
            }
        }
}

// ---------------- GEMM2: h2 = bf16(g1r @ W2), A already bf16 (relu pre-applied) ----------------
// Block 128x64, 4 waves, wave tile 32x64 (2x4 mtiles). K=128.

__global__ __launch_bounds__(256) void gemm2_mfma(const unsigned short* __restrict__ G,
                                                  const unsigned short* __restrict__ W2T,
                                                  unsigned short* __restrict__ H2, int M) {
    __shared__ __align__(16) unsigned short As[128 * 136];
    __shared__ __align__(16) unsigned short Bs[64 * 136];
    const int tid = threadIdx.x;
    const int lane = tid & 63;
    const int w = tid >> 6;
    const int row0 = blockIdx.x * 128;

    #pragma unroll
    for (int l = 0; l < 8; ++l) {
        int f = tid + l * 256;                 // 2048 ushort8
        int r = f >> 4, k8 = f & 15;
        int row = row0 + r;
        us8 v{};
        if (row < M) v = *reinterpret_cast<const us8*>(&G[(size_t)row * HID_CH + k8 * 8]);
        *reinterpret_cast<us8*>(&As[r * 136 + k8 * 8]) = v;
    }
    #pragma unroll
    for (int l = 0; l < 4; ++l) {
        int f = tid + l * 256;                 // 1024 ushort8
        int n = f >> 4, k8 = f & 15;
        us8 v = *reinterpret_cast<const us8*>(&W2T[n * 128 + k8 * 8]);
        *reinterpret_cast<us8*>(&Bs[n * 136 + k8 * 8]) = v;
    }
    __syncthreads();

    f32x4 acc[2][4] = {};
    const int lr = lane & 15;
    const int kb = (lane >> 4) * 8;
    #pragma unroll
    for (int kk = 0; kk < 4; ++kk) {
        bfrag8 a0 = *reinterpret_cast<const bfrag8*>(&As[(w * 32 + lr) * 136 + kk * 32 + kb]);
        bfrag8 a1 = *reinterpret_cast<const bfrag8*>(&As[(w * 32 + 16 + lr) * 136 + kk * 32 + kb]);
        #pragma unroll
        for (int ni = 0; ni < 4; ++ni) {
            bfrag8 b = *reinterpret_cast<const bfrag8*>(&Bs[(ni * 16 + lr) * 136 + kk * 32 + kb]);
            acc[0][ni] = __builtin_amdgcn_mfma_f32_16x16x32_bf16(a0, b, acc[0][ni], 0, 0, 0);
            acc[1][ni] = __builtin_amdgcn_mfma_f32_16x16x32_bf16(a1, b, acc[1][ni], 0, 0, 0);
        }
    }
    const int rb = row0 + w * 32 + (lane >> 4) * 4;
    #pragma unroll
    for (int mi = 0; mi < 2; ++mi)
        #pragma unroll
        for (int j = 0; j < 4; ++j) {
            int row = rb + mi * 16 + j;
            if (row < M) {
                #pragma unroll
                for (int ni = 0; ni < 4; ++ni)
                    H2[(size_t)row * OUT_CH + ni * 16 + lr] = f2bf(acc[mi][ni][j]);
            }
        }
}

// ---------------- SpMM: out[i] = sum_e val[e] * h[src[e]], bf16 payload ----------------
// D/8 lanes per node, us8 (16B) gathers, 4x unrolled for gather ILP.
// Edge stream is packed (src:int, val:f32) int2.
// MODE 0: out = f32. MODE 1: out = bf16(relu(acc)).

template <int D, int MODE>
__global__ __launch_bounds__(256) void spmm_bf16(const int* __restrict__ row_ptr,
                                                 const int2* __restrict__ sval,
                                                 const unsigned short* __restrict__ h,
                                                 void* __restrict__ outp, int n) {
    constexpr int TPN = D / 8;
    constexpr int NPB = 256 / TPN;
    int node = blockIdx.x * NPB + threadIdx.x / TPN;
    if (node >= n) return;
    int c8 = (threadIdx.x % TPN) * 8;
    int s = row_ptr[node], e = row_ptr[node + 1];
    float acc[8] = {};
    int i = s;
    for (; i + 4 <= e; i += 4) {
        int2 e0 = sval[i + 0], e1 = sval[i + 1], e2 = sval[i + 2], e3 = sval[i + 3];
        float v0 = __int_as_float(e0.y), v1 = __int_as_float(e1.y);
        float v2 = __int_as_float(e2.y), v3 = __int_as_float(e3.y);
        us8 m0 = *reinterpret_cast<const us8*>(&h[(size_t)e0.x * D + c8]);
        us8 m1 = *reinterpret_cast<const us8*>(&h[(size_t)e1.x * D + c8]);
        us8 m2 = *reinterpret_cast<const us8*>(&h[(size_t)e2.x * D + c8]);
        us8 m3 = *reinterpret_cast<const us8*>(&h[(size_t)e3.x * D + c8]);
        #pragma unroll
        for (int j = 0; j < 8; ++j) {
            acc[j] += v0 * bf2f(m0[j]);
            acc[j] += v1 * bf2f(m1[j]);
            acc[j] += v2 * bf2f(m2[j]);
            acc[j] += v3 * bf2f(m3[j]);
        }
    }
    for (; i < e; ++i) {
        int2 e0 = sval[i];
        float v = __int_as_float(e0.y);
        us8 m = *reinterpret_cast<const us8*>(&h[(size_t)e0.x * D + c8]);
        #pragma unroll
        for (int j = 0; j < 8; ++j) acc[j] += v * bf2f(m[j]);
    }
    if (MODE == 1) {
        us8 o;
        #pragma unroll
        for (int j = 0; j < 8; ++j) o[j] = f2bf(fmaxf(acc[j], 0.f));
        *reinterpret_cast<us8*>(&((unsigned short*)outp)[(size_t)node * D + c8]) = o;
    } else {
        float* op = (float*)outp;
        float4 w0 = make_float4(acc[0], acc[1], acc[2], acc[3]);
        float4 w1 = make_float4(acc[4], acc[5], acc[6], acc[7]);
        *reinterpret_cast<float4*>(&op[(size_t)node * D + c8]) = w0;
        *reinterpret_cast<float4*>(&op[(size_t)node * D + c8 + 4]) = w1;
    }
}

// ---------------- launch ----------------

extern "C" void kernel_launch(void* const* d_in, const int* in_sizes, int n_in,
                              void* d_out, int out_size, void* d_ws, size_t ws_size,
                              hipStream_t stream) {
    const float* x  = (const float*)d_in[0];
    const float* W1 = (const float*)d_in[1];
    const float* W2 = (const float*)d_in[2];
    const float* ev = (const float*)d_in[3];
    const int*   ei = (const int*)d_in[4];

    const int N = in_sizes[0] / IN_CH;   // 100000
    const int E = in_sizes[3];           // 1600000
    const int* src = ei;
    const int* dst = ei + E;

    const int NBUCK = (N + 255) >> 8;                    // 391
    const int G1 = 256;                                  // level-1 blocks
    const int CH = (E + G1 - 1) / G1;                    // 6250 edges/block
    const int NB_TOT = NBUCK * G1;                       // 100096
    const int nchunk = (NB_TOT + 1023) / 1024;           // 98

    // workspace layout (~78 MB); h2 aliases h1 (h1 dead after spmm1)
    unsigned short* h1   = (unsigned short*)d_ws;        // N*128 bf16
    unsigned short* g1r  = h1 + (size_t)N * HID_CH;      // N*128 bf16 (relu applied)
    unsigned short* h2   = h1;                           // N*64 bf16 (alias)
    unsigned short* w1t  = g1r + (size_t)N * HID_CH;     // 128*128 bf16 [n][k]
    unsigned short* w2t  = w1t + 128 * 128;              // 64*128 bf16 [n][k]
    int2*  sval    = (int2*)(w2t + 64 * 128);            // E packed (src, val)
    int2*  ebuf    = sval + E;                           // E bucketed intermediate
    int*   row_ptr = (int*)(ebuf + E);                   // N+1
    int*   bcnt    = row_ptr + (N + 1);                  // NB_TOT (scan in place)
    int*   btot    = bcnt + NB_TOT;                      // 128
    int*   bb      = btot + 128;                         // NBUCK+1

    // CSR build (LDS atomics only)
    cnt1<<<G1, 256, 0, stream>>>(dst, bcnt, E, CH, NBUCK, G1);
    scanA<<<nchunk, 1024, 0, stream>>>(bcnt, bcnt, btot, NB_TOT);
    scanB<<<1, 128, 0, stream>>>(btot, nchunk);
    scanC2<<<nchunk, 1024, 0, stream>>>(bcnt, btot, NB_TOT);
    bbk<<<1, 512, 0, stream>>>(bcnt, bb, NBUCK, G1, E);
    scat1<<<G1, 256, 0, stream>>>(src, dst, ev, bcnt, ebuf, E, CH, NBUCK, G1);
    sort2<<<NBUCK, 256, 0, stream>>>(ebuf, bb, sval, row_ptr, N, NBUCK, E);

    // weights: cast + transpose to [n][k] bf16
    castT_w1<<<64, 256, 0, stream>>>(W1, w1t);
    castT_w2<<<32, 256, 0, stream>>>(W2, w2t);

    // layer 1
    gemm1_mfma<<<(N + 127) / 128, 256, 0, stream>>>(x, w1t, h1, N);
    spmm_bf16<HID_CH, 1><<<(N + 15) / 16, 256, 0, stream>>>(row_ptr, sval, h1, g1r, N);

    // layer 2
    gemm2_mfma<<<(N + 127) / 128, 256, 0, stream>>>(g1r, w2t, h2, N);
    spmm_bf16<OUT_CH, 0><<<(N + 31) / 32, 256, 0, stream>>>(row_ptr, sval, h2, (float*)d_out, N);
}